// Round 1
// 262.195 us; speedup vs baseline: 1.0149x; 1.0149x over previous
//
#include <hip/hip_runtime.h>
#include <hip/hip_bf16.h>
#include <math.h>

#define NN 4096
#define DD 256

typedef __bf16 bf16x8 __attribute__((ext_vector_type(8)));
typedef short  short8 __attribute__((ext_vector_type(8)));
typedef float  f32x4  __attribute__((ext_vector_type(4)));

#define MFMA16(a, b, c) __builtin_amdgcn_mfma_f32_16x16x32_bf16((a), (b), (c), 0, 0, 0)

__device__ inline bf16x8 brelu(bf16x8 a) {
    short8 s = __builtin_bit_cast(short8, a);
    s = s & ~(s >> 15);            // negative (sign bit set) -> 0, else keep
    return __builtin_bit_cast(bf16x8, s);
}

__device__ inline float wave_red(float v) {
#pragma unroll
    for (int o = 32; o > 0; o >>= 1) v += __shfl_down(v, o, 64);
    return v;
}

__device__ inline unsigned short bfbits(float f) {
    return __builtin_bit_cast(unsigned short, (__bf16)f);
}

// ---------------- prep: 64x64 LDS-tiled transpose; cur/pre -> bf16 (+T) ----------------
__global__ __launch_bounds__(256) void k_prep(const float* __restrict__ cur,
                                              const float* __restrict__ pre,
                                              __bf16* __restrict__ cur_bf,
                                              __bf16* __restrict__ curT,
                                              __bf16* __restrict__ preT) {
    const int z = blockIdx.z;
    const int i0 = blockIdx.x * 64, d0 = blockIdx.y * 64;
    const float* src = z ? pre : cur;
    __bf16* dstT = z ? preT : curT;
    __shared__ unsigned short tile[64][72];
    const int t = threadIdx.x;
    const int r = t >> 2, c4 = (t & 3) * 16;
    const float* srow = src + (size_t)(i0 + r) * DD + d0 + c4;
    alignas(16) unsigned short loc[16];
#pragma unroll
    for (int e = 0; e < 4; ++e) {
        float4 v = ((const float4*)srow)[e];
        loc[e * 4 + 0] = bfbits(v.x);
        loc[e * 4 + 1] = bfbits(v.y);
        loc[e * 4 + 2] = bfbits(v.z);
        loc[e * 4 + 3] = bfbits(v.w);
    }
#pragma unroll
    for (int e = 0; e < 16; ++e) tile[r][c4 + e] = loc[e];
    if (z == 0) {
        __bf16* drow = cur_bf + (size_t)(i0 + r) * DD + d0 + c4;
        *(uint4*)drow = *(uint4*)&loc[0];
        *(uint4*)(drow + 8) = *(uint4*)&loc[8];
    }
    __syncthreads();
    alignas(16) unsigned short o[16];
#pragma unroll
    for (int e = 0; e < 16; ++e) o[e] = tile[c4 + e][r];
    __bf16* trow = dstT + (size_t)(d0 + r) * NN + i0 + c4;
    *(uint4*)trow = *(uint4*)&o[0];
    *(uint4*)(trow + 8) = *(uint4*)&o[8];
}

// ---------------- proj matrices -> bf16 transposed ([n][k]); theta_w as-is ----------------
__global__ __launch_bounds__(256) void k_proj(
    const float* __restrict__ a0, const float* __restrict__ a1, const float* __restrict__ a2,
    const float* __restrict__ a3, const float* __restrict__ a4, const float* __restrict__ a5,
    __bf16* __restrict__ o0, __bf16* __restrict__ o1, __bf16* __restrict__ o2,
    __bf16* __restrict__ o3, __bf16* __restrict__ o4, __bf16* __restrict__ o5) {
    const int id = blockIdx.y, r = blockIdx.x, t = threadIdx.x;
    const float* src = id == 0 ? a0 : id == 1 ? a1 : id == 2 ? a2 : id == 3 ? a3 : id == 4 ? a4 : a5;
    __bf16* dst = id == 0 ? o0 : id == 1 ? o1 : id == 2 ? o2 : id == 3 ? o3 : id == 4 ? o4 : o5;
    float v = src[r * DD + t];
    if (id < 5) dst[t * DD + r] = (__bf16)v;   // transposed: T[n][k] = src[k][n]
    else        dst[r * DD + t] = (__bf16)v;   // theta_w stays [j][k] (that IS B^T layout)
}

// ---------------- incidence_t -> bf16, rowsum(relu), per-block |x| and x^2 partials ----------------
__global__ __launch_bounds__(256) void k_conv_t(const float* __restrict__ inc,
                                                __bf16* __restrict__ Mbf,
                                                float* __restrict__ rowsum,
                                                float* __restrict__ pAbs, float* __restrict__ pSq) {
    const int i = blockIdx.x, t = threadIdx.x;
    const float4* src = (const float4*)(inc + (size_t)i * NN);
    ushort4* dst = (ushort4*)(Mbf + (size_t)i * NN);
    float rs = 0.f, as = 0.f, qs = 0.f;
#pragma unroll
    for (int e = 0; e < 4; ++e) {
        const int f = t + 256 * e;
        float4 v = src[f];
        float x[4] = {v.x, v.y, v.z, v.w};
        unsigned short o[4];
#pragma unroll
        for (int j = 0; j < 4; ++j) {
            float fv = x[j];
            as += fabsf(fv); qs += fv * fv; rs += fmaxf(fv, 0.f);
            o[j] = bfbits(fv);
        }
        dst[f] = make_ushort4(o[0], o[1], o[2], o[3]);
    }
    __shared__ float red[3][4];
    const int w = t >> 6, lane = t & 63;
    rs = wave_red(rs); as = wave_red(as); qs = wave_red(qs);
    if (lane == 0) { red[0][w] = rs; red[1][w] = as; red[2][w] = qs; }
    __syncthreads();
    if (t == 0) {
        rowsum[i] = red[0][0] + red[0][1] + red[0][2] + red[0][3];
        pAbs[i]   = red[1][0] + red[1][1] + red[1][2] + red[1][3];
        pSq[i]    = red[2][0] + red[2][1] + red[2][2] + red[2][3];
    }
}

// ---------------- incidence_s [N,N-1] -> zero-diag [N,N] bf16 via LDS scatter + partials ----------------
__global__ __launch_bounds__(256) void k_conv_s(const float* __restrict__ inc,
                                                __bf16* __restrict__ Mbf,
                                                float* __restrict__ rowsum,
                                                float* __restrict__ pAbs, float* __restrict__ pSq) {
    const int i = blockIdx.x, t = threadIdx.x;
    __shared__ unsigned short row[NN];     // 8 KB staging for the scattered output row
    const float* srow = inc + (size_t)i * (NN - 1);
    float rs = 0.f, as = 0.f, qs = 0.f;
#pragma unroll
    for (int e = 0; e < 4; ++e) {
        const int f = t + 256 * e;         // float4-group index within row, [0,1024)
        float x[4] = {0.f, 0.f, 0.f, 0.f};
        if (f < 1023) __builtin_memcpy(x, srow + 4 * f, 16);   // row base only 4B-aligned
        else          __builtin_memcpy(x, srow + 4092, 12);    // tail: 3 valid floats
#pragma unroll
        for (int j = 0; j < 4; ++j) {
            const int k = 4 * f + j;
            float fv = x[j];
            as += fabsf(fv); qs += fv * fv; rs += fmaxf(fv, 0.f);
            if (k < NN - 1) row[k + (k >= i)] = bfbits(fv);
        }
    }
    if (t == 0) row[i] = 0;                // diagonal
    __syncthreads();
    uint4* dOut = (uint4*)(Mbf + (size_t)i * NN);
    const uint4* sIn = (const uint4*)row;
    dOut[t] = sIn[t];
    dOut[t + 256] = sIn[t + 256];
    __shared__ float red[3][4];
    const int w = t >> 6, lane = t & 63;
    rs = wave_red(rs); as = wave_red(as); qs = wave_red(qs);
    if (lane == 0) { red[0][w] = rs; red[1][w] = as; red[2][w] = qs; }
    __syncthreads();
    if (t == 0) {
        rowsum[i] = red[0][0] + red[0][1] + red[0][2] + red[0][3];
        pAbs[i]   = red[1][0] + red[1][1] + red[1][2] + red[1][3];
        pSq[i]    = red[2][0] + red[2][1] + red[2][2] + red[2][3];
    }
}

// ---------------- shared MFMA inner step (64x64 tile, BK=64, 4 waves in 2x2) ----------------
template <int DUAL>
__device__ inline void mfma_step(const __bf16 (&As)[64][72], const __bf16 (&Bs)[64][72],
                                 int wr, int wc, int quad, int l16,
                                 f32x4 (&accR)[2][2], f32x4 (&accL)[2][2]) {
#pragma unroll
    for (int ks = 0; ks < 2; ++ks) {
        const int kc = ks * 32 + quad * 8;
        bf16x8 a0 = *(const bf16x8*)&As[wr * 32 + l16][kc];
        bf16x8 a1 = *(const bf16x8*)&As[wr * 32 + 16 + l16][kc];
        bf16x8 b0 = *(const bf16x8*)&Bs[wc * 32 + l16][kc];
        bf16x8 b1 = *(const bf16x8*)&Bs[wc * 32 + 16 + l16][kc];
        accR[0][0] = MFMA16(a0, b0, accR[0][0]);
        accR[0][1] = MFMA16(a0, b1, accR[0][1]);
        accR[1][0] = MFMA16(a1, b0, accR[1][0]);
        accR[1][1] = MFMA16(a1, b1, accR[1][1]);
        if (DUAL) {
            bf16x8 a0r = brelu(a0), a1r = brelu(a1);
            accL[0][0] = MFMA16(a0r, b0, accL[0][0]);
            accL[0][1] = MFMA16(a0r, b1, accL[0][1]);
            accL[1][0] = MFMA16(a1r, b0, accL[1][0]);
            accL[1][1] = MFMA16(a1r, b1, accL[1][1]);
        }
    }
}

// ---------------- big dual GEMM: raw (for fro-diff) + relu (for edge features) ----------------
// Pipelined: 1-deep register prefetch + LDS double-buffer, one raw s_barrier per K-iter
// (vmcnt is never drained inside the loop), XCD-chunked block swizzle for A-panel L2 reuse,
// bf16 emb = (relu-GEMM + cur)/deg written directly (deg from k_conv rowsums).
__global__ __launch_bounds__(256) void k_big(const __bf16* __restrict__ Mt, const __bf16* __restrict__ Ms,
                                             const __bf16* __restrict__ preT, const __bf16* __restrict__ curT,
                                             const float* __restrict__ negMt, const float* __restrict__ negMs,
                                             const float* __restrict__ cur,
                                             const float* __restrict__ rsT, const float* __restrict__ rsS,
                                             __bf16* __restrict__ embT, __bf16* __restrict__ embS,
                                             float* __restrict__ pDiff) {
    // XCD-chunked remap (512 blocks, 512%8==0 -> bijective): the 4 blocks sharing an
    // A row-panel (same y) land on one XCD so each 512KB panel is fetched once per L2.
    const int flat = blockIdx.x + 4 * (blockIdx.y + 64 * blockIdx.z);
    const int swz = (flat & 7) * 64 + (flat >> 3);
    const int bx = swz & 3, by = (swz >> 2) & 63, z = swz >> 8;
    const __bf16* A  = z ? Ms : Mt;
    const __bf16* BT = z ? curT : preT;
    const float* negM = z ? negMs : negMt;
    const float* rs   = z ? rsS : rsT;
    __bf16* emb       = z ? embS : embT;
    const int n0 = bx * 64, m0 = by * 64;
    __shared__ __bf16 As[2][64][72], Bs[2][64][72];
    __shared__ float sred[4];
    f32x4 accR[2][2], accL[2][2];
#pragma unroll
    for (int i = 0; i < 2; ++i)
#pragma unroll
        for (int j = 0; j < 2; ++j) { accR[i][j] = (f32x4)0.f; accL[i][j] = (f32x4)0.f; }
    const int t = threadIdx.x, w = t >> 6, lane = t & 63, quad = lane >> 4, l16 = lane & 15;
    const int wr = w >> 1, wc = w & 1;
    const int sr = t >> 2, sc = (t & 3) * 16;
    const __bf16* gA = A + (size_t)(m0 + sr) * NN + sc;
    const __bf16* gB = BT + (size_t)(n0 + sr) * NN + sc;
    // prologue: tile 0 -> LDS[0]; issue tile 1 into regs (stays in flight across the barrier)
    uint4 av0 = *(const uint4*)(gA);
    uint4 av1 = *(const uint4*)(gA + 8);
    uint4 bv0 = *(const uint4*)(gB);
    uint4 bv1 = *(const uint4*)(gB + 8);
    gA += 64; gB += 64;
    *(uint4*)&As[0][sr][sc] = av0; *(uint4*)&As[0][sr][sc + 8] = av1;
    *(uint4*)&Bs[0][sr][sc] = bv0; *(uint4*)&Bs[0][sr][sc + 8] = bv1;
    av0 = *(const uint4*)(gA);
    av1 = *(const uint4*)(gA + 8);
    bv0 = *(const uint4*)(gB);
    bv1 = *(const uint4*)(gB + 8);
    gA += 64; gB += 64;
    __builtin_amdgcn_sched_barrier(0);
    asm volatile("s_waitcnt lgkmcnt(0)" ::: "memory");
    __builtin_amdgcn_s_barrier();
    int c = 0;
    for (int kt = 0; kt < NN / 64; ++kt) {
        __builtin_amdgcn_s_setprio(1);
        mfma_step<1>(As[c], Bs[c], wr, wc, quad, l16, accR, accL);
        __builtin_amdgcn_s_setprio(0);
        if (kt < NN / 64 - 1) {
            // write next tile (dep-wait on its loads, issued one iter ago), then
            // issue the tile after into the same regs — loads fly across the barrier
            *(uint4*)&As[c ^ 1][sr][sc] = av0; *(uint4*)&As[c ^ 1][sr][sc + 8] = av1;
            *(uint4*)&Bs[c ^ 1][sr][sc] = bv0; *(uint4*)&Bs[c ^ 1][sr][sc + 8] = bv1;
            if (kt < NN / 64 - 2) {
                av0 = *(const uint4*)(gA);
                av1 = *(const uint4*)(gA + 8);
                bv0 = *(const uint4*)(gB);
                bv1 = *(const uint4*)(gB + 8);
                gA += 64; gB += 64;
            }
            __builtin_amdgcn_sched_barrier(0);
            asm volatile("s_waitcnt lgkmcnt(0)" ::: "memory");   // own ds_writes landed
        }
        __builtin_amdgcn_s_barrier();                            // raw: no vmcnt drain
        c ^= 1;
    }
    float sumd = 0.f;
#pragma unroll
    for (int mi = 0; mi < 2; ++mi)
#pragma unroll
        for (int ni = 0; ni < 2; ++ni)
#pragma unroll
            for (int r = 0; r < 4; ++r) {
                int gr = m0 + wr * 32 + mi * 16 + quad * 4 + r;
                int gc = n0 + wc * 32 + ni * 16 + l16;
                size_t idx = (size_t)gr * DD + gc;
                float diff = accR[mi][ni][r] + negM[idx];   // recon - master
                sumd += diff * diff;
                float inv = 1.f / (rs[gr] + 1.f);
                emb[idx] = (__bf16)((accL[mi][ni][r] + cur[idx]) * inv);  // normalized edge emb
            }
    sumd = wave_red(sumd);
    if (lane == 0) sred[w] = sumd;
    __syncthreads();
    if (t == 0)
        pDiff[z * 256 + by * 4 + bx] = sred[0] + sred[1] + sred[2] + sred[3];
}

// ---------------- small GEMMs: -master_s, -master_t, node_fea ----------------
__global__ __launch_bounds__(256) void k_small3(const __bf16* __restrict__ cur_bf,
                                                const __bf16* __restrict__ pTs, const __bf16* __restrict__ pTt,
                                                const __bf16* __restrict__ pTn,
                                                float* __restrict__ negMs, float* __restrict__ negMt,
                                                float* __restrict__ nodeFea) {
    const int z = blockIdx.z;
    const __bf16* BT = z == 0 ? pTs : (z == 1 ? pTt : pTn);
    const int n0 = blockIdx.x * 64, m0 = blockIdx.y * 64;
    __shared__ __bf16 As[64][72], Bs[64][72];
    f32x4 accR[2][2];
#pragma unroll
    for (int i = 0; i < 2; ++i)
#pragma unroll
        for (int j = 0; j < 2; ++j) accR[i][j] = (f32x4)0.f;
    const int t = threadIdx.x, w = t >> 6, lane = t & 63, quad = lane >> 4, l16 = lane & 15;
    const int wr = w >> 1, wc = w & 1;
    const int sr = t >> 2, sc = (t & 3) * 16;
    const __bf16* gA = cur_bf + (size_t)(m0 + sr) * DD + sc;
    const __bf16* gB = BT + (size_t)(n0 + sr) * DD + sc;
    for (int kt = 0; kt < DD / 64; ++kt) {
        uint4 av0 = *(const uint4*)(gA);
        uint4 av1 = *(const uint4*)(gA + 8);
        uint4 bv0 = *(const uint4*)(gB);
        uint4 bv1 = *(const uint4*)(gB + 8);
        __syncthreads();
        *(uint4*)&As[sr][sc] = av0; *(uint4*)&As[sr][sc + 8] = av1;
        *(uint4*)&Bs[sr][sc] = bv0; *(uint4*)&Bs[sr][sc + 8] = bv1;
        __syncthreads();
        mfma_step<0>(As, Bs, wr, wc, quad, l16, accR, accR);
        gA += 64; gB += 64;
    }
#pragma unroll
    for (int mi = 0; mi < 2; ++mi)
#pragma unroll
        for (int ni = 0; ni < 2; ++ni)
#pragma unroll
            for (int r = 0; r < 4; ++r) {
                int gr = m0 + wr * 32 + mi * 16 + quad * 4 + r;
                int gc = n0 + wc * 32 + ni * 16 + l16;
                size_t idx = (size_t)gr * DD + gc;
                float v = accR[mi][ni][r];
                if (z == 0) negMs[idx] = -v;
                else if (z == 1) negMt[idx] = -v;
                else nodeFea[idx] = v;
            }
}

// ---------------- edge-feature projections: spa_fea / tmp_fea (bf16 emb input) ----------------
__global__ __launch_bounds__(256) void k_fea(const __bf16* __restrict__ embS, const __bf16* __restrict__ embT,
                                             const __bf16* __restrict__ pTspa, const __bf16* __restrict__ pTtmp,
                                             float* __restrict__ spaF, float* __restrict__ tmpF) {
    const int z = blockIdx.z;
    const __bf16* Ae = z ? embT : embS;
    const __bf16* BT = z ? pTtmp : pTspa;
    float* outF = z ? tmpF : spaF;
    const int n0 = blockIdx.x * 64, m0 = blockIdx.y * 64;
    __shared__ __bf16 As[64][72], Bs[64][72];
    f32x4 accR[2][2];
#pragma unroll
    for (int i = 0; i < 2; ++i)
#pragma unroll
        for (int j = 0; j < 2; ++j) accR[i][j] = (f32x4)0.f;
    const int t = threadIdx.x, w = t >> 6, lane = t & 63, quad = lane >> 4, l16 = lane & 15;
    const int wr = w >> 1, wc = w & 1;
    const int sr = t >> 2, sc = (t & 3) * 16;
    const __bf16* gA = Ae + (size_t)(m0 + sr) * DD + sc;
    const __bf16* gB = BT + (size_t)(n0 + sr) * DD + sc;
    for (int kt = 0; kt < DD / 64; ++kt) {
        uint4 av0 = *(const uint4*)(gA);
        uint4 av1 = *(const uint4*)(gA + 8);
        uint4 bv0 = *(const uint4*)(gB);
        uint4 bv1 = *(const uint4*)(gB + 8);
        __syncthreads();
        *(uint4*)&As[sr][sc] = av0; *(uint4*)&As[sr][sc + 8] = av1;
        *(uint4*)&Bs[sr][sc] = bv0; *(uint4*)&Bs[sr][sc + 8] = bv1;
        __syncthreads();
        mfma_step<0>(As, Bs, wr, wc, quad, l16, accR, accR);
        gA += 64; gB += 64;
    }
#pragma unroll
    for (int mi = 0; mi < 2; ++mi)
#pragma unroll
        for (int ni = 0; ni < 2; ++ni)
#pragma unroll
            for (int r = 0; r < 4; ++r) {
                int gr = m0 + wr * 32 + mi * 16 + quad * 4 + r;
                int gc = n0 + wc * 32 + ni * 16 + l16;
                outF[(size_t)gr * DD + gc] = accR[mi][ni][r];
            }
}

// ---------------- attention scalars ----------------
__global__ __launch_bounds__(256) void k_attn(const float* __restrict__ spaF, const float* __restrict__ tmpF,
                                              const float* __restrict__ nodeF,
                                              float* __restrict__ spaA, float* __restrict__ tmpA) {
    const int t = threadIdx.x, w = t >> 6, lane = t & 63;
    const int i = blockIdx.x * 4 + w;
    const float4* sf = (const float4*)(spaF + (size_t)i * DD);
    const float4* tf = (const float4*)(tmpF + (size_t)i * DD);
    const float4* nf = (const float4*)(nodeF + (size_t)i * DD);
    float4 s = sf[lane], p = tf[lane], n = nf[lane];
    float ds = s.x * n.x + s.y * n.y + s.z * n.z + s.w * n.w;
    float dt = p.x * n.x + p.y * n.y + p.z * n.z + p.w * n.w;
    ds = wave_red(ds); dt = wave_red(dt);
    if (lane == 0) { spaA[i] = ds * 0.0625f; tmpA[i] = dt * 0.0625f; }  // 1/sqrt(256)
}

// ---------------- final: val @ theta_w^T + b, relu -> d_out ----------------
__global__ __launch_bounds__(256) void k_final(const float* __restrict__ spaF, const float* __restrict__ tmpF,
                                               const float* __restrict__ spaA, const float* __restrict__ tmpA,
                                               const __bf16* __restrict__ thetaBf, const float* __restrict__ thetaB,
                                               float* __restrict__ out) {
    const int n0 = blockIdx.x * 64, m0 = blockIdx.y * 64;
    __shared__ __bf16 As[64][72], Bs[64][72];
    f32x4 accR[2][2];
#pragma unroll
    for (int i = 0; i < 2; ++i)
#pragma unroll
        for (int j = 0; j < 2; ++j) accR[i][j] = (f32x4)0.f;
    const int t = threadIdx.x, w = t >> 6, lane = t & 63, quad = lane >> 4, l16 = lane & 15;
    const int wr = w >> 1, wc = w & 1;
    const int sr = t >> 2, sc = (t & 3) * 16;
    const float sa = spaA[m0 + sr], ta = tmpA[m0 + sr];
    const float* gS = spaF + (size_t)(m0 + sr) * DD + sc;
    const float* gT = tmpF + (size_t)(m0 + sr) * DD + sc;
    const __bf16* gB = thetaBf + (size_t)(n0 + sr) * DD + sc;
    for (int kt = 0; kt < DD / 64; ++kt) {
        __bf16 tmp[16];
#pragma unroll
        for (int e4 = 0; e4 < 4; ++e4) {
            float4 vs = ((const float4*)gS)[e4];
            float4 vt = ((const float4*)gT)[e4];
            tmp[e4 * 4 + 0] = (__bf16)(sa * vs.x + ta * vt.x);
            tmp[e4 * 4 + 1] = (__bf16)(sa * vs.y + ta * vt.y);
            tmp[e4 * 4 + 2] = (__bf16)(sa * vs.z + ta * vt.z);
            tmp[e4 * 4 + 3] = (__bf16)(sa * vs.w + ta * vt.w);
        }
        uint4 bv0 = *(const uint4*)(gB);
        uint4 bv1 = *(const uint4*)(gB + 8);
        __syncthreads();
        *(uint4*)&As[sr][sc] = *(uint4*)&tmp[0]; *(uint4*)&As[sr][sc + 8] = *(uint4*)&tmp[8];
        *(uint4*)&Bs[sr][sc] = bv0; *(uint4*)&Bs[sr][sc + 8] = bv1;
        __syncthreads();
        mfma_step<0>(As, Bs, wr, wc, quad, l16, accR, accR);
        gS += 64; gT += 64; gB += 64;
    }
#pragma unroll
    for (int mi = 0; mi < 2; ++mi)
#pragma unroll
        for (int ni = 0; ni < 2; ++ni)
#pragma unroll
            for (int r = 0; r < 4; ++r) {
                int gr = m0 + wr * 32 + mi * 16 + quad * 4 + r;
                int gc = n0 + wc * 32 + ni * 16 + l16;
                float v = accR[mi][ni][r] + thetaB[gc];
                out[(size_t)gr * DD + gc] = fmaxf(v, 0.f);
            }
}

// ---------------- loss: reduce per-block partials, single block ----------------
__global__ __launch_bounds__(256) void k_loss(const float* __restrict__ pAbsT, const float* __restrict__ pSqT,
                                              const float* __restrict__ pAbsS, const float* __restrict__ pSqS,
                                              const float* __restrict__ pDiff,
                                              float* __restrict__ out) {
    const int t = threadIdx.x;
    float aT = 0.f, qT = 0.f, aS = 0.f, qS = 0.f;
#pragma unroll
    for (int j = 0; j < 16; ++j) {
        const int i = t + 256 * j;
        aT += pAbsT[i]; qT += pSqT[i]; aS += pAbsS[i]; qS += pSqS[i];
    }
    float dT = pDiff[t], dS = pDiff[256 + t];
    aT = wave_red(aT); qT = wave_red(qT); aS = wave_red(aS); qS = wave_red(qS);
    dT = wave_red(dT); dS = wave_red(dS);
    __shared__ float red[6][4];
    const int w = t >> 6, lane = t & 63;
    if (lane == 0) { red[0][w] = aT; red[1][w] = qT; red[2][w] = aS; red[3][w] = qS; red[4][w] = dT; red[5][w] = dS; }
    __syncthreads();
    if (t == 0) {
        float s[6];
#pragma unroll
        for (int k = 0; k < 6; ++k) s[k] = red[k][0] + red[k][1] + red[k][2] + red[k][3];
        float l = s[0] + 0.001f * sqrtf(s[1]) + 0.2f * sqrtf(s[4])    // temporal
                + s[2] + 0.001f * sqrtf(s[3]) + 0.2f * sqrtf(s[5]);   // spatial
        out[(size_t)NN * DD] = l;
    }
}

extern "C" void kernel_launch(void* const* d_in, const int* in_sizes, int n_in,
                              void* d_out, int out_size, void* d_ws, size_t ws_size,
                              hipStream_t stream) {
    (void)in_sizes; (void)n_in; (void)out_size; (void)ws_size;
    const float* cur      = (const float*)d_in[0];
    const float* pre      = (const float*)d_in[1];
    const float* r_proj_s = (const float*)d_in[2];
    const float* inc_s    = (const float*)d_in[3];
    const float* r_proj_t = (const float*)d_in[4];
    const float* inc_t    = (const float*)d_in[5];
    const float* node_pj  = (const float*)d_in[6];
    const float* spa_pj   = (const float*)d_in[7];
    const float* tmp_pj   = (const float*)d_in[8];
    const float* theta_w  = (const float*)d_in[9];
    const float* theta_b  = (const float*)d_in[10];
    float* out = (float*)d_out;

    char* p = (char*)d_ws;
    auto alloc = [&](size_t bytes) -> void* {
        void* r = (void*)p;
        p += (bytes + 255) & ~(size_t)255;
        return r;
    };
    __bf16* Mt      = (__bf16*)alloc((size_t)NN * NN * 2);
    __bf16* Ms      = (__bf16*)alloc((size_t)NN * NN * 2);
    __bf16* cur_bf  = (__bf16*)alloc((size_t)NN * DD * 2);
    __bf16* curT    = (__bf16*)alloc((size_t)NN * DD * 2);
    __bf16* preT    = (__bf16*)alloc((size_t)NN * DD * 2);
    __bf16* pTs     = (__bf16*)alloc((size_t)DD * DD * 2);
    __bf16* pTt     = (__bf16*)alloc((size_t)DD * DD * 2);
    __bf16* pTn     = (__bf16*)alloc((size_t)DD * DD * 2);
    __bf16* pTspa   = (__bf16*)alloc((size_t)DD * DD * 2);
    __bf16* pTtmp   = (__bf16*)alloc((size_t)DD * DD * 2);
    __bf16* thetaBf = (__bf16*)alloc((size_t)DD * DD * 2);
    __bf16* embS    = (__bf16*)alloc((size_t)NN * DD * 2);
    __bf16* embT    = (__bf16*)alloc((size_t)NN * DD * 2);
    float* negMs    = (float*)alloc((size_t)NN * DD * 4);
    float* negMt    = (float*)alloc((size_t)NN * DD * 4);
    float* nodeFea  = (float*)alloc((size_t)NN * DD * 4);
    float* spaF     = (float*)alloc((size_t)NN * DD * 4);
    float* tmpF     = (float*)alloc((size_t)NN * DD * 4);
    float* rsS      = (float*)alloc((size_t)NN * 4);
    float* rsT      = (float*)alloc((size_t)NN * 4);
    float* spaA     = (float*)alloc((size_t)NN * 4);
    float* tmpA     = (float*)alloc((size_t)NN * 4);
    float* pAbsT    = (float*)alloc((size_t)NN * 4);
    float* pSqT     = (float*)alloc((size_t)NN * 4);
    float* pAbsS    = (float*)alloc((size_t)NN * 4);
    float* pSqS     = (float*)alloc((size_t)NN * 4);
    float* pDiff    = (float*)alloc(512 * 4);

    k_prep<<<dim3(NN / 64, DD / 64, 2), 256, 0, stream>>>(cur, pre, cur_bf, curT, preT);
    k_proj<<<dim3(DD, 6), 256, 0, stream>>>(r_proj_s, r_proj_t, node_pj, spa_pj, tmp_pj, theta_w,
                                            pTs, pTt, pTn, pTspa, pTtmp, thetaBf);
    k_conv_t<<<NN, 256, 0, stream>>>(inc_t, Mt, rsT, pAbsT, pSqT);
    k_conv_s<<<NN, 256, 0, stream>>>(inc_s, Ms, rsS, pAbsS, pSqS);
    k_small3<<<dim3(4, 64, 3), 256, 0, stream>>>(cur_bf, pTs, pTt, pTn, negMs, negMt, nodeFea);
    k_big<<<dim3(4, 64, 2), 256, 0, stream>>>(Mt, Ms, preT, curT, negMt, negMs, cur,
                                              rsT, rsS, embT, embS, pDiff);
    k_fea<<<dim3(4, 64, 2), 256, 0, stream>>>(embS, embT, pTspa, pTtmp, spaF, tmpF);
    k_attn<<<NN / 4, 256, 0, stream>>>(spaF, tmpF, nodeFea, spaA, tmpA);
    k_final<<<dim3(4, 64), 256, 0, stream>>>(spaF, tmpF, spaA, tmpA, thetaBf, theta_b, out);
    k_loss<<<1, 256, 0, stream>>>(pAbsT, pSqT, pAbsS, pSqS, pDiff, out);
}

// Round 2
// 255.320 us; speedup vs baseline: 1.0423x; 1.0269x over previous
//
#include <hip/hip_runtime.h>
#include <hip/hip_bf16.h>
#include <math.h>

#define NN 4096
#define DD 256

typedef __bf16 bf16x8 __attribute__((ext_vector_type(8)));
typedef short  short8 __attribute__((ext_vector_type(8)));
typedef float  f32x4  __attribute__((ext_vector_type(4)));

typedef __attribute__((address_space(1))) const void gv_t;
typedef __attribute__((address_space(3))) void lv_t;
#define GLD16(gp, lp) __builtin_amdgcn_global_load_lds((gv_t*)(gp), (lv_t*)(lp), 16, 0, 0)

#define MFMA16(a, b, c) __builtin_amdgcn_mfma_f32_16x16x32_bf16((a), (b), (c), 0, 0, 0)

__device__ inline bf16x8 brelu(bf16x8 a) {
    short8 s = __builtin_bit_cast(short8, a);
    s = s & ~(s >> 15);            // negative (sign bit set) -> 0, else keep
    return __builtin_bit_cast(bf16x8, s);
}

__device__ inline float wave_red(float v) {
#pragma unroll
    for (int o = 32; o > 0; o >>= 1) v += __shfl_down(v, o, 64);
    return v;
}

__device__ inline unsigned short bfbits(float f) {
    return __builtin_bit_cast(unsigned short, (__bf16)f);
}

// ---------------- prep: 64x64 LDS-tiled transpose; cur/pre -> bf16 (+T) ----------------
__global__ __launch_bounds__(256) void k_prep(const float* __restrict__ cur,
                                              const float* __restrict__ pre,
                                              __bf16* __restrict__ cur_bf,
                                              __bf16* __restrict__ curT,
                                              __bf16* __restrict__ preT) {
    const int z = blockIdx.z;
    const int i0 = blockIdx.x * 64, d0 = blockIdx.y * 64;
    const float* src = z ? pre : cur;
    __bf16* dstT = z ? preT : curT;
    __shared__ unsigned short tile[64][72];
    const int t = threadIdx.x;
    const int r = t >> 2, c4 = (t & 3) * 16;
    const float* srow = src + (size_t)(i0 + r) * DD + d0 + c4;
    alignas(16) unsigned short loc[16];
#pragma unroll
    for (int e = 0; e < 4; ++e) {
        float4 v = ((const float4*)srow)[e];
        loc[e * 4 + 0] = bfbits(v.x);
        loc[e * 4 + 1] = bfbits(v.y);
        loc[e * 4 + 2] = bfbits(v.z);
        loc[e * 4 + 3] = bfbits(v.w);
    }
#pragma unroll
    for (int e = 0; e < 16; ++e) tile[r][c4 + e] = loc[e];
    if (z == 0) {
        __bf16* drow = cur_bf + (size_t)(i0 + r) * DD + d0 + c4;
        *(uint4*)drow = *(uint4*)&loc[0];
        *(uint4*)(drow + 8) = *(uint4*)&loc[8];
    }
    __syncthreads();
    alignas(16) unsigned short o[16];
#pragma unroll
    for (int e = 0; e < 16; ++e) o[e] = tile[c4 + e][r];
    __bf16* trow = dstT + (size_t)(d0 + r) * NN + i0 + c4;
    *(uint4*)trow = *(uint4*)&o[0];
    *(uint4*)(trow + 8) = *(uint4*)&o[8];
}

// ---------------- proj matrices -> bf16 transposed ([n][k]); theta_w as-is ----------------
__global__ __launch_bounds__(256) void k_proj(
    const float* __restrict__ a0, const float* __restrict__ a1, const float* __restrict__ a2,
    const float* __restrict__ a3, const float* __restrict__ a4, const float* __restrict__ a5,
    __bf16* __restrict__ o0, __bf16* __restrict__ o1, __bf16* __restrict__ o2,
    __bf16* __restrict__ o3, __bf16* __restrict__ o4, __bf16* __restrict__ o5) {
    const int id = blockIdx.y, r = blockIdx.x, t = threadIdx.x;
    const float* src = id == 0 ? a0 : id == 1 ? a1 : id == 2 ? a2 : id == 3 ? a3 : id == 4 ? a4 : a5;
    __bf16* dst = id == 0 ? o0 : id == 1 ? o1 : id == 2 ? o2 : id == 3 ? o3 : id == 4 ? o4 : o5;
    float v = src[r * DD + t];
    if (id < 5) dst[t * DD + r] = (__bf16)v;   // transposed: T[n][k] = src[k][n]
    else        dst[r * DD + t] = (__bf16)v;   // theta_w stays [j][k] (that IS B^T layout)
}

// ---------------- incidence_t -> bf16, rowsum(relu), per-block |x| and x^2 partials ----------------
__global__ __launch_bounds__(256) void k_conv_t(const float* __restrict__ inc,
                                                __bf16* __restrict__ Mbf,
                                                float* __restrict__ rowsum,
                                                float* __restrict__ pAbs, float* __restrict__ pSq) {
    const int i = blockIdx.x, t = threadIdx.x;
    const float4* src = (const float4*)(inc + (size_t)i * NN);
    ushort4* dst = (ushort4*)(Mbf + (size_t)i * NN);
    float rs = 0.f, as = 0.f, qs = 0.f;
#pragma unroll
    for (int e = 0; e < 4; ++e) {
        const int f = t + 256 * e;
        float4 v = src[f];
        float x[4] = {v.x, v.y, v.z, v.w};
        unsigned short o[4];
#pragma unroll
        for (int j = 0; j < 4; ++j) {
            float fv = x[j];
            as += fabsf(fv); qs += fv * fv; rs += fmaxf(fv, 0.f);
            o[j] = bfbits(fv);
        }
        dst[f] = make_ushort4(o[0], o[1], o[2], o[3]);
    }
    __shared__ float red[3][4];
    const int w = t >> 6, lane = t & 63;
    rs = wave_red(rs); as = wave_red(as); qs = wave_red(qs);
    if (lane == 0) { red[0][w] = rs; red[1][w] = as; red[2][w] = qs; }
    __syncthreads();
    if (t == 0) {
        rowsum[i] = red[0][0] + red[0][1] + red[0][2] + red[0][3];
        pAbs[i]   = red[1][0] + red[1][1] + red[1][2] + red[1][3];
        pSq[i]    = red[2][0] + red[2][1] + red[2][2] + red[2][3];
    }
}

// ---------------- incidence_s [N,N-1] -> zero-diag [N,N] bf16 via LDS scatter + partials ----------------
__global__ __launch_bounds__(256) void k_conv_s(const float* __restrict__ inc,
                                                __bf16* __restrict__ Mbf,
                                                float* __restrict__ rowsum,
                                                float* __restrict__ pAbs, float* __restrict__ pSq) {
    const int i = blockIdx.x, t = threadIdx.x;
    __shared__ unsigned short row[NN];     // 8 KB staging for the scattered output row
    const float* srow = inc + (size_t)i * (NN - 1);
    float rs = 0.f, as = 0.f, qs = 0.f;
#pragma unroll
    for (int e = 0; e < 4; ++e) {
        const int f = t + 256 * e;         // float4-group index within row, [0,1024)
        float x[4] = {0.f, 0.f, 0.f, 0.f};
        if (f < 1023) __builtin_memcpy(x, srow + 4 * f, 16);   // row base only 4B-aligned
        else          __builtin_memcpy(x, srow + 4092, 12);    // tail: 3 valid floats
#pragma unroll
        for (int j = 0; j < 4; ++j) {
            const int k = 4 * f + j;
            float fv = x[j];
            as += fabsf(fv); qs += fv * fv; rs += fmaxf(fv, 0.f);
            if (k < NN - 1) row[k + (k >= i)] = bfbits(fv);
        }
    }
    if (t == 0) row[i] = 0;                // diagonal
    __syncthreads();
    uint4* dOut = (uint4*)(Mbf + (size_t)i * NN);
    const uint4* sIn = (const uint4*)row;
    dOut[t] = sIn[t];
    dOut[t + 256] = sIn[t + 256];
    __shared__ float red[3][4];
    const int w = t >> 6, lane = t & 63;
    rs = wave_red(rs); as = wave_red(as); qs = wave_red(qs);
    if (lane == 0) { red[0][w] = rs; red[1][w] = as; red[2][w] = qs; }
    __syncthreads();
    if (t == 0) {
        rowsum[i] = red[0][0] + red[0][1] + red[0][2] + red[0][3];
        pAbs[i]   = red[1][0] + red[1][1] + red[1][2] + red[1][3];
        pSq[i]    = red[2][0] + red[2][1] + red[2][2] + red[2][3];
    }
}

// ---------------- shared MFMA inner step for the small (padded-LDS) GEMMs ----------------
__device__ inline void mfma_step_s(const __bf16 (&As)[64][72], const __bf16 (&Bs)[64][72],
                                   int wr, int wc, int quad, int l16,
                                   f32x4 (&accR)[2][2]) {
#pragma unroll
    for (int ks = 0; ks < 2; ++ks) {
        const int kc = ks * 32 + quad * 8;
        bf16x8 a0 = *(const bf16x8*)&As[wr * 32 + l16][kc];
        bf16x8 a1 = *(const bf16x8*)&As[wr * 32 + 16 + l16][kc];
        bf16x8 b0 = *(const bf16x8*)&Bs[wc * 32 + l16][kc];
        bf16x8 b1 = *(const bf16x8*)&Bs[wc * 32 + 16 + l16][kc];
        accR[0][0] = MFMA16(a0, b0, accR[0][0]);
        accR[0][1] = MFMA16(a0, b1, accR[0][1]);
        accR[1][0] = MFMA16(a1, b0, accR[1][0]);
        accR[1][1] = MFMA16(a1, b1, accR[1][1]);
    }
}

// ---------------- big dual GEMM: raw (for fro-diff) + relu (for edge features) ----------------
// global_load_lds staging (linear LDS, both-sides XOR chunk swizzle), 2-buffer pipeline with
// counted vmcnt(4) (never drained in-loop), two raw s_barriers per K-step, XCD-chunked swizzle.
__global__ __launch_bounds__(256) void k_big(const __bf16* __restrict__ Mt, const __bf16* __restrict__ Ms,
                                             const __bf16* __restrict__ preT, const __bf16* __restrict__ curT,
                                             const float* __restrict__ negMt, const float* __restrict__ negMs,
                                             const float* __restrict__ cur,
                                             const float* __restrict__ rsT, const float* __restrict__ rsS,
                                             __bf16* __restrict__ embT, __bf16* __restrict__ embS,
                                             float* __restrict__ pDiff) {
    const int flat = blockIdx.x + 4 * (blockIdx.y + 64 * blockIdx.z);
    const int swz = (flat & 7) * 64 + (flat >> 3);
    const int bx = swz & 3, by = (swz >> 2) & 63, z = swz >> 8;
    const __bf16* A  = z ? Ms : Mt;
    const __bf16* BT = z ? curT : preT;
    const float* negM = z ? negMs : negMt;
    const float* rs   = z ? rsS : rsT;
    __bf16* emb       = z ? embS : embT;
    const int n0 = bx * 64, m0 = by * 64;
    __shared__ __bf16 sm[2][2][64][64];    // [buf][A=0/B=1][row][col], linear, 32 KB
    __shared__ float sred[4];
    f32x4 accR[2][2], accL[2][2];
#pragma unroll
    for (int i = 0; i < 2; ++i)
#pragma unroll
        for (int j = 0; j < 2; ++j) { accR[i][j] = (f32x4)0.f; accL[i][j] = (f32x4)0.f; }
    const int t = threadIdx.x, w = t >> 6, lane = t & 63, quad = lane >> 4, l16 = lane & 15;
    const int wr = w >> 1, wc = w & 1;
    // --- staging addressing: wave w stages chunks {2w,2w+1} of A and of B (1 KB each) ---
    // chunk q = LDS rows [8q,8q+8); lane -> row 8q+(lane>>3), 16B col-chunk lane&7.
    // source is chunk-XOR-preswizzled so reads can XOR by (row&7) (rule #21: both sides).
    const int lr = lane >> 3, lc = lane & 7;
    const int q0 = 2 * w, q1 = q0 + 1;
    const int csw = ((lc ^ lr) * 8);
    const __bf16* gA0 = A + (size_t)(m0 + 8 * q0 + lr) * NN + csw;
    const __bf16* gA1 = A + (size_t)(m0 + 8 * q1 + lr) * NN + csw;
    const __bf16* gB0 = BT + (size_t)(n0 + 8 * q0 + lr) * NN + csw;
    const __bf16* gB1 = BT + (size_t)(n0 + 8 * q1 + lr) * NN + csw;
    auto stage = [&](int b, int tk) {
        const int ko = tk * 64;
        GLD16(gA0 + ko, &sm[b][0][8 * q0][0]);
        GLD16(gA1 + ko, &sm[b][0][8 * q1][0]);
        GLD16(gB0 + ko, &sm[b][1][8 * q0][0]);
        GLD16(gB1 + ko, &sm[b][1][8 * q1][0]);
    };
    // prologue: tiles 0,1 in flight; wait only for tile 0 (vmcnt(4))
    stage(0, 0);
    stage(1, 1);
    asm volatile("s_waitcnt vmcnt(4)" ::: "memory");
    __builtin_amdgcn_s_barrier();
    __builtin_amdgcn_sched_barrier(0);
    const int h8 = l16 & 7;
    const int ra0 = wr * 32 + l16, ra1 = ra0 + 16;
    const int rb0 = wc * 32 + l16, rb1 = rb0 + 16;
    int c = 0;
    const int NT = NN / 64;
    for (int kt = 0; kt < NT; ++kt) {
        bf16x8 a0k[2], a1k[2], b0k[2], b1k[2];
#pragma unroll
        for (int ks = 0; ks < 2; ++ks) {
            const int sw = ((4 * ks + quad) ^ h8) * 8;   // swizzled 16B chunk
            a0k[ks] = *(const bf16x8*)&sm[c][0][ra0][sw];
            a1k[ks] = *(const bf16x8*)&sm[c][0][ra1][sw];
            b0k[ks] = *(const bf16x8*)&sm[c][1][rb0][sw];
            b1k[ks] = *(const bf16x8*)&sm[c][1][rb1][sw];
        }
        asm volatile("s_waitcnt lgkmcnt(0)" ::: "memory");   // fragments in regs
        __builtin_amdgcn_sched_barrier(0);
        __builtin_amdgcn_s_barrier();                        // buf c free for overwrite
        __builtin_amdgcn_sched_barrier(0);
        if (kt < NT - 2) stage(c, kt + 2);                   // DMA into freed buf
        __builtin_amdgcn_sched_barrier(0);
        __builtin_amdgcn_s_setprio(1);
#pragma unroll
        for (int ks = 0; ks < 2; ++ks) {
            accR[0][0] = MFMA16(a0k[ks], b0k[ks], accR[0][0]);
            accR[0][1] = MFMA16(a0k[ks], b1k[ks], accR[0][1]);
            accR[1][0] = MFMA16(a1k[ks], b0k[ks], accR[1][0]);
            accR[1][1] = MFMA16(a1k[ks], b1k[ks], accR[1][1]);
            bf16x8 a0r = brelu(a0k[ks]), a1r = brelu(a1k[ks]);
            accL[0][0] = MFMA16(a0r, b0k[ks], accL[0][0]);
            accL[0][1] = MFMA16(a0r, b1k[ks], accL[0][1]);
            accL[1][0] = MFMA16(a1r, b0k[ks], accL[1][0]);
            accL[1][1] = MFMA16(a1r, b1k[ks], accL[1][1]);
        }
        __builtin_amdgcn_s_setprio(0);
        if (kt < NT - 1) {
            if (kt < NT - 2) asm volatile("s_waitcnt vmcnt(4)" ::: "memory");  // next tile landed
            else             asm volatile("s_waitcnt vmcnt(0)" ::: "memory");  // last tile
            __builtin_amdgcn_s_barrier();
            __builtin_amdgcn_sched_barrier(0);
        }
        c ^= 1;
    }
    float sumd = 0.f;
#pragma unroll
    for (int mi = 0; mi < 2; ++mi)
#pragma unroll
        for (int ni = 0; ni < 2; ++ni)
#pragma unroll
            for (int r = 0; r < 4; ++r) {
                int gr = m0 + wr * 32 + mi * 16 + quad * 4 + r;
                int gc = n0 + wc * 32 + ni * 16 + l16;
                size_t idx = (size_t)gr * DD + gc;
                float diff = accR[mi][ni][r] + negM[idx];   // recon - master
                sumd += diff * diff;
                float inv = 1.f / (rs[gr] + 1.f);
                emb[idx] = (__bf16)((accL[mi][ni][r] + cur[idx]) * inv);  // normalized edge emb
            }
    sumd = wave_red(sumd);
    if (lane == 0) sred[w] = sumd;
    __syncthreads();
    if (t == 0)
        pDiff[z * 256 + by * 4 + bx] = sred[0] + sred[1] + sred[2] + sred[3];
}

// ---------------- small GEMMs: -master_s, -master_t, node_fea ----------------
__global__ __launch_bounds__(256) void k_small3(const __bf16* __restrict__ cur_bf,
                                                const __bf16* __restrict__ pTs, const __bf16* __restrict__ pTt,
                                                const __bf16* __restrict__ pTn,
                                                float* __restrict__ negMs, float* __restrict__ negMt,
                                                float* __restrict__ nodeFea) {
    const int z = blockIdx.z;
    const __bf16* BT = z == 0 ? pTs : (z == 1 ? pTt : pTn);
    const int n0 = blockIdx.x * 64, m0 = blockIdx.y * 64;
    __shared__ __bf16 As[64][72], Bs[64][72];
    f32x4 accR[2][2];
#pragma unroll
    for (int i = 0; i < 2; ++i)
#pragma unroll
        for (int j = 0; j < 2; ++j) accR[i][j] = (f32x4)0.f;
    const int t = threadIdx.x, w = t >> 6, lane = t & 63, quad = lane >> 4, l16 = lane & 15;
    const int wr = w >> 1, wc = w & 1;
    const int sr = t >> 2, sc = (t & 3) * 16;
    const __bf16* gA = cur_bf + (size_t)(m0 + sr) * DD + sc;
    const __bf16* gB = BT + (size_t)(n0 + sr) * DD + sc;
    for (int kt = 0; kt < DD / 64; ++kt) {
        uint4 av0 = *(const uint4*)(gA);
        uint4 av1 = *(const uint4*)(gA + 8);
        uint4 bv0 = *(const uint4*)(gB);
        uint4 bv1 = *(const uint4*)(gB + 8);
        __syncthreads();
        *(uint4*)&As[sr][sc] = av0; *(uint4*)&As[sr][sc + 8] = av1;
        *(uint4*)&Bs[sr][sc] = bv0; *(uint4*)&Bs[sr][sc + 8] = bv1;
        __syncthreads();
        mfma_step_s(As, Bs, wr, wc, quad, l16, accR);
        gA += 64; gB += 64;
    }
#pragma unroll
    for (int mi = 0; mi < 2; ++mi)
#pragma unroll
        for (int ni = 0; ni < 2; ++ni)
#pragma unroll
            for (int r = 0; r < 4; ++r) {
                int gr = m0 + wr * 32 + mi * 16 + quad * 4 + r;
                int gc = n0 + wc * 32 + ni * 16 + l16;
                size_t idx = (size_t)gr * DD + gc;
                float v = accR[mi][ni][r];
                if (z == 0) negMs[idx] = -v;
                else if (z == 1) negMt[idx] = -v;
                else nodeFea[idx] = v;
            }
}

// ---------------- edge-feature projections + fused attention partial dots ----------------
__global__ __launch_bounds__(256) void k_fea(const __bf16* __restrict__ embS, const __bf16* __restrict__ embT,
                                             const __bf16* __restrict__ pTspa, const __bf16* __restrict__ pTtmp,
                                             const float* __restrict__ nodeF,
                                             float* __restrict__ spaF, float* __restrict__ tmpF,
                                             float* __restrict__ pSpa, float* __restrict__ pTmp) {
    const int z = blockIdx.z;
    const __bf16* Ae = z ? embT : embS;
    const __bf16* BT = z ? pTtmp : pTspa;
    float* outF = z ? tmpF : spaF;
    float* pOut = z ? pTmp : pSpa;
    const int n0 = blockIdx.x * 64, m0 = blockIdx.y * 64;
    __shared__ __bf16 As[64][72], Bs[64][72];
    f32x4 accR[2][2];
#pragma unroll
    for (int i = 0; i < 2; ++i)
#pragma unroll
        for (int j = 0; j < 2; ++j) accR[i][j] = (f32x4)0.f;
    const int t = threadIdx.x, w = t >> 6, lane = t & 63, quad = lane >> 4, l16 = lane & 15;
    const int wr = w >> 1, wc = w & 1;
    const int sr = t >> 2, sc = (t & 3) * 16;
    const __bf16* gA = Ae + (size_t)(m0 + sr) * DD + sc;
    const __bf16* gB = BT + (size_t)(n0 + sr) * DD + sc;
    for (int kt = 0; kt < DD / 64; ++kt) {
        uint4 av0 = *(const uint4*)(gA);
        uint4 av1 = *(const uint4*)(gA + 8);
        uint4 bv0 = *(const uint4*)(gB);
        uint4 bv1 = *(const uint4*)(gB + 8);
        __syncthreads();
        *(uint4*)&As[sr][sc] = av0; *(uint4*)&As[sr][sc + 8] = av1;
        *(uint4*)&Bs[sr][sc] = bv0; *(uint4*)&Bs[sr][sc + 8] = bv1;
        __syncthreads();
        mfma_step_s(As, Bs, wr, wc, quad, l16, accR);
        gA += 64; gB += 64;
    }
    // epilogue: write fea, and per-row partial dot with nodeF for the attention scalars.
    // slice index bx*2+wc keeps writers unique (two wc-waves share rows).
    const int slice = blockIdx.x * 2 + wc;
#pragma unroll
    for (int mi = 0; mi < 2; ++mi)
#pragma unroll
        for (int r = 0; r < 4; ++r) {
            const int gr = m0 + wr * 32 + mi * 16 + quad * 4 + r;
            float s = 0.f;
#pragma unroll
            for (int ni = 0; ni < 2; ++ni) {
                const int gc = n0 + wc * 32 + ni * 16 + l16;
                const size_t idx = (size_t)gr * DD + gc;
                const float v = accR[mi][ni][r];
                outF[idx] = v;
                s += v * nodeF[idx];
            }
            s += __shfl_xor(s, 1, 64);
            s += __shfl_xor(s, 2, 64);
            s += __shfl_xor(s, 4, 64);
            s += __shfl_xor(s, 8, 64);
            if (l16 == 0) pOut[(size_t)slice * NN + gr] = s;
        }
}

// ---------------- final: val @ theta_w^T + b, relu -> d_out ----------------
__global__ __launch_bounds__(256) void k_final(const float* __restrict__ spaF, const float* __restrict__ tmpF,
                                               const float* __restrict__ pSpa, const float* __restrict__ pTmp,
                                               const __bf16* __restrict__ thetaBf, const float* __restrict__ thetaB,
                                               float* __restrict__ out) {
    const int n0 = blockIdx.x * 64, m0 = blockIdx.y * 64;
    __shared__ __bf16 As[64][72], Bs[64][72];
    f32x4 accR[2][2];
#pragma unroll
    for (int i = 0; i < 2; ++i)
#pragma unroll
        for (int j = 0; j < 2; ++j) accR[i][j] = (f32x4)0.f;
    const int t = threadIdx.x, w = t >> 6, lane = t & 63, quad = lane >> 4, l16 = lane & 15;
    const int wr = w >> 1, wc = w & 1;
    const int sr = t >> 2, sc = (t & 3) * 16;
    const int row = m0 + sr;
    float sa = 0.f, ta = 0.f;
#pragma unroll
    for (int j = 0; j < 8; ++j) {
        sa += pSpa[(size_t)j * NN + row];
        ta += pTmp[(size_t)j * NN + row];
    }
    sa *= 0.0625f; ta *= 0.0625f;   // 1/sqrt(256)
    const float* gS = spaF + (size_t)row * DD + sc;
    const float* gT = tmpF + (size_t)row * DD + sc;
    const __bf16* gB = thetaBf + (size_t)(n0 + sr) * DD + sc;
    for (int kt = 0; kt < DD / 64; ++kt) {
        __bf16 tmp[16];
#pragma unroll
        for (int e4 = 0; e4 < 4; ++e4) {
            float4 vs = ((const float4*)gS)[e4];
            float4 vt = ((const float4*)gT)[e4];
            tmp[e4 * 4 + 0] = (__bf16)(sa * vs.x + ta * vt.x);
            tmp[e4 * 4 + 1] = (__bf16)(sa * vs.y + ta * vt.y);
            tmp[e4 * 4 + 2] = (__bf16)(sa * vs.z + ta * vt.z);
            tmp[e4 * 4 + 3] = (__bf16)(sa * vs.w + ta * vt.w);
        }
        uint4 bv0 = *(const uint4*)(gB);
        uint4 bv1 = *(const uint4*)(gB + 8);
        __syncthreads();
        *(uint4*)&As[sr][sc] = *(uint4*)&tmp[0]; *(uint4*)&As[sr][sc + 8] = *(uint4*)&tmp[8];
        *(uint4*)&Bs[sr][sc] = bv0; *(uint4*)&Bs[sr][sc + 8] = bv1;
        __syncthreads();
        mfma_step_s(As, Bs, wr, wc, quad, l16, accR);
        gS += 64; gT += 64; gB += 64;
    }
#pragma unroll
    for (int mi = 0; mi < 2; ++mi)
#pragma unroll
        for (int ni = 0; ni < 2; ++ni)
#pragma unroll
            for (int r = 0; r < 4; ++r) {
                int gr = m0 + wr * 32 + mi * 16 + quad * 4 + r;
                int gc = n0 + wc * 32 + ni * 16 + l16;
                float v = accR[mi][ni][r] + thetaB[gc];
                out[(size_t)gr * DD + gc] = fmaxf(v, 0.f);
            }
}

// ---------------- loss: reduce per-block partials, single block ----------------
__global__ __launch_bounds__(256) void k_loss(const float* __restrict__ pAbsT, const float* __restrict__ pSqT,
                                              const float* __restrict__ pAbsS, const float* __restrict__ pSqS,
                                              const float* __restrict__ pDiff,
                                              float* __restrict__ out) {
    const int t = threadIdx.x;
    float aT = 0.f, qT = 0.f, aS = 0.f, qS = 0.f;
#pragma unroll
    for (int j = 0; j < 16; ++j) {
        const int i = t + 256 * j;
        aT += pAbsT[i]; qT += pSqT[i]; aS += pAbsS[i]; qS += pSqS[i];
    }
    float dT = pDiff[t], dS = pDiff[256 + t];
    aT = wave_red(aT); qT = wave_red(qT); aS = wave_red(aS); qS = wave_red(qS);
    dT = wave_red(dT); dS = wave_red(dS);
    __shared__ float red[6][4];
    const int w = t >> 6, lane = t & 63;
    if (lane == 0) { red[0][w] = aT; red[1][w] = qT; red[2][w] = aS; red[3][w] = qS; red[4][w] = dT; red[5][w] = dS; }
    __syncthreads();
    if (t == 0) {
        float s[6];
#pragma unroll
        for (int k = 0; k < 6; ++k) s[k] = red[k][0] + red[k][1] + red[k][2] + red[k][3];
        float l = s[0] + 0.001f * sqrtf(s[1]) + 0.2f * sqrtf(s[4])    // temporal
                + s[2] + 0.001f * sqrtf(s[3]) + 0.2f * sqrtf(s[5]);   // spatial
        out[(size_t)NN * DD] = l;
    }
}

extern "C" void kernel_launch(void* const* d_in, const int* in_sizes, int n_in,
                              void* d_out, int out_size, void* d_ws, size_t ws_size,
                              hipStream_t stream) {
    (void)in_sizes; (void)n_in; (void)out_size; (void)ws_size;
    const float* cur      = (const float*)d_in[0];
    const float* pre      = (const float*)d_in[1];
    const float* r_proj_s = (const float*)d_in[2];
    const float* inc_s    = (const float*)d_in[3];
    const float* r_proj_t = (const float*)d_in[4];
    const float* inc_t    = (const float*)d_in[5];
    const float* node_pj  = (const float*)d_in[6];
    const float* spa_pj   = (const float*)d_in[7];
    const float* tmp_pj   = (const float*)d_in[8];
    const float* theta_w  = (const float*)d_in[9];
    const float* theta_b  = (const float*)d_in[10];
    float* out = (float*)d_out;

    char* p = (char*)d_ws;
    auto alloc = [&](size_t bytes) -> void* {
        void* r = (void*)p;
        p += (bytes + 255) & ~(size_t)255;
        return r;
    };
    __bf16* Mt      = (__bf16*)alloc((size_t)NN * NN * 2);
    __bf16* Ms      = (__bf16*)alloc((size_t)NN * NN * 2);
    __bf16* cur_bf  = (__bf16*)alloc((size_t)NN * DD * 2);
    __bf16* curT    = (__bf16*)alloc((size_t)NN * DD * 2);
    __bf16* preT    = (__bf16*)alloc((size_t)NN * DD * 2);
    __bf16* pTs     = (__bf16*)alloc((size_t)DD * DD * 2);
    __bf16* pTt     = (__bf16*)alloc((size_t)DD * DD * 2);
    __bf16* pTn     = (__bf16*)alloc((size_t)DD * DD * 2);
    __bf16* pTspa   = (__bf16*)alloc((size_t)DD * DD * 2);
    __bf16* pTtmp   = (__bf16*)alloc((size_t)DD * DD * 2);
    __bf16* thetaBf = (__bf16*)alloc((size_t)DD * DD * 2);
    __bf16* embS    = (__bf16*)alloc((size_t)NN * DD * 2);
    __bf16* embT    = (__bf16*)alloc((size_t)NN * DD * 2);
    float* negMs    = (float*)alloc((size_t)NN * DD * 4);
    float* negMt    = (float*)alloc((size_t)NN * DD * 4);
    float* nodeFea  = (float*)alloc((size_t)NN * DD * 4);
    float* spaF     = (float*)alloc((size_t)NN * DD * 4);
    float* tmpF     = (float*)alloc((size_t)NN * DD * 4);
    float* rsS      = (float*)alloc((size_t)NN * 4);
    float* rsT      = (float*)alloc((size_t)NN * 4);
    float* pSpa     = (float*)alloc((size_t)8 * NN * 4);
    float* pTmp     = (float*)alloc((size_t)8 * NN * 4);
    float* pAbsT    = (float*)alloc((size_t)NN * 4);
    float* pSqT     = (float*)alloc((size_t)NN * 4);
    float* pAbsS    = (float*)alloc((size_t)NN * 4);
    float* pSqS     = (float*)alloc((size_t)NN * 4);
    float* pDiff    = (float*)alloc(512 * 4);

    k_prep<<<dim3(NN / 64, DD / 64, 2), 256, 0, stream>>>(cur, pre, cur_bf, curT, preT);
    k_proj<<<dim3(DD, 6), 256, 0, stream>>>(r_proj_s, r_proj_t, node_pj, spa_pj, tmp_pj, theta_w,
                                            pTs, pTt, pTn, pTspa, pTtmp, thetaBf);
    k_conv_t<<<NN, 256, 0, stream>>>(inc_t, Mt, rsT, pAbsT, pSqT);
    k_conv_s<<<NN, 256, 0, stream>>>(inc_s, Ms, rsS, pAbsS, pSqS);
    k_small3<<<dim3(4, 64, 3), 256, 0, stream>>>(cur_bf, pTs, pTt, pTn, negMs, negMt, nodeFea);
    k_big<<<dim3(4, 64, 2), 256, 0, stream>>>(Mt, Ms, preT, curT, negMt, negMs, cur,
                                              rsT, rsS, embT, embS, pDiff);
    k_fea<<<dim3(4, 64, 2), 256, 0, stream>>>(embS, embT, pTspa, pTtmp, nodeFea,
                                              spaF, tmpF, pSpa, pTmp);
    k_final<<<dim3(4, 64), 256, 0, stream>>>(spaF, tmpF, pSpa, pTmp, thetaBf, theta_b, out);
    k_loss<<<1, 256, 0, stream>>>(pAbsT, pSqT, pAbsS, pSqS, pDiff, out);
}

// Round 3
// 243.654 us; speedup vs baseline: 1.0922x; 1.0479x over previous
//
#include <hip/hip_runtime.h>
#include <hip/hip_bf16.h>
#include <math.h>

#define NN 4096
#define DD 256

typedef __bf16 bf16x8 __attribute__((ext_vector_type(8)));
typedef short  short8 __attribute__((ext_vector_type(8)));
typedef float  f32x4  __attribute__((ext_vector_type(4)));
typedef float  f32x16 __attribute__((ext_vector_type(16)));

typedef __attribute__((address_space(1))) const void gv_t;
typedef __attribute__((address_space(3))) void lv_t;
#define GLD16(gp, lp) __builtin_amdgcn_global_load_lds((gv_t*)(gp), (lv_t*)(lp), 16, 0, 0)

#define MFMA16(a, b, c) __builtin_amdgcn_mfma_f32_16x16x32_bf16((a), (b), (c), 0, 0, 0)
#define MFMA32(a, b, c) __builtin_amdgcn_mfma_f32_32x32x16_bf16((a), (b), (c), 0, 0, 0)

__device__ inline bf16x8 brelu(bf16x8 a) {
    short8 s = __builtin_bit_cast(short8, a);
    s = s & ~(s >> 15);            // negative (sign bit set) -> 0, else keep
    return __builtin_bit_cast(bf16x8, s);
}

__device__ inline float wave_red(float v) {
#pragma unroll
    for (int o = 32; o > 0; o >>= 1) v += __shfl_down(v, o, 64);
    return v;
}

__device__ inline unsigned short bfbits(float f) {
    return __builtin_bit_cast(unsigned short, (__bf16)f);
}

__device__ inline void syncb() {
    asm volatile("s_waitcnt lgkmcnt(0)" ::: "memory");
    __builtin_amdgcn_s_barrier();
}

// store/load one 32x32 f32 fragment (16 regs/lane) to a 4KB LDS slot, bank-balanced:
// layout [r4 0..3][lane][4 floats] -> per instr lanes stride 16B, uniform 8 accesses/bank.
__device__ inline void store16(float* base, const f32x16& v, int lane) {
#pragma unroll
    for (int r4 = 0; r4 < 4; ++r4) {
        f32x4 c = {v[4 * r4], v[4 * r4 + 1], v[4 * r4 + 2], v[4 * r4 + 3]};
        ((f32x4*)base)[r4 * 64 + lane] = c;
    }
}
__device__ inline void add16(f32x16& v, const float* base, int lane) {
#pragma unroll
    for (int r4 = 0; r4 < 4; ++r4) {
        f32x4 c = ((const f32x4*)base)[r4 * 64 + lane];
        v[4 * r4] += c[0]; v[4 * r4 + 1] += c[1]; v[4 * r4 + 2] += c[2]; v[4 * r4 + 3] += c[3];
    }
}

// cross-wave K-split reduction: wave W ends owning quadrant (mi=W>>1, ni=W&1), fully
// summed over all 4 waves' K-slices. 2 rounds R + 2 rounds L, 8 slots of 4KB scratch.
// All indices compile-time (rule #20); every wave executes the same barrier count.
template <int W>
__device__ inline void red_owner(f32x16 (&aR)[2][2], f32x16 (&aL)[2][2],
                                 float* scr, int lane, f32x16& oR, f32x16& oL) {
    constexpr int o1 = W ^ 1, o2 = W ^ 2, o3 = W ^ 3;
    store16(scr + W * 1024,       aR[o1 >> 1][o1 & 1], lane);
    store16(scr + (4 + W) * 1024, aR[o2 >> 1][o2 & 1], lane);
    syncb();
    oR = aR[W >> 1][W & 1];
    add16(oR, scr + o1 * 1024, lane);
    add16(oR, scr + (4 + o2) * 1024, lane);
    syncb();
    store16(scr + W * 1024, aR[o3 >> 1][o3 & 1], lane);
    syncb();
    add16(oR, scr + o3 * 1024, lane);
    syncb();
    store16(scr + W * 1024,       aL[o1 >> 1][o1 & 1], lane);
    store16(scr + (4 + W) * 1024, aL[o2 >> 1][o2 & 1], lane);
    syncb();
    oL = aL[W >> 1][W & 1];
    add16(oL, scr + o1 * 1024, lane);
    add16(oL, scr + (4 + o2) * 1024, lane);
    syncb();
    store16(scr + W * 1024, aL[o3 >> 1][o3 & 1], lane);
    syncb();
    add16(oL, scr + o3 * 1024, lane);
}

// ---------------- merged preprocessing: conv_t | conv_s | prep | proj ----------------
__global__ __launch_bounds__(256) void k_pre(
    const float* __restrict__ cur, const float* __restrict__ pre,
    const float* __restrict__ r_proj_s, const float* __restrict__ r_proj_t,
    const float* __restrict__ node_pj, const float* __restrict__ spa_pj,
    const float* __restrict__ tmp_pj, const float* __restrict__ theta_w,
    const float* __restrict__ inc_t, const float* __restrict__ inc_s,
    __bf16* __restrict__ cur_bf, __bf16* __restrict__ curT, __bf16* __restrict__ preT,
    __bf16* __restrict__ pTs, __bf16* __restrict__ pTt, __bf16* __restrict__ pTn,
    __bf16* __restrict__ pTspa, __bf16* __restrict__ pTtmp, __bf16* __restrict__ thetaBf,
    __bf16* __restrict__ Mt, __bf16* __restrict__ Ms,
    float* __restrict__ rsT, float* __restrict__ pAbsT, float* __restrict__ pSqT,
    float* __restrict__ rsS, float* __restrict__ pAbsS, float* __restrict__ pSqS) {
    __shared__ __align__(16) char psm[9280];
    const int b = blockIdx.x, t = threadIdx.x;
    if (b < 4096) {
        // ---- conv_t: incidence_t -> bf16, relu-rowsum, |x| and x^2 partials ----
        const int i = b;
        float (*red)[4] = (float (*)[4])psm;
        const float4* src = (const float4*)(inc_t + (size_t)i * NN);
        ushort4* dst = (ushort4*)(Mt + (size_t)i * NN);
        float rs = 0.f, as = 0.f, qs = 0.f;
#pragma unroll
        for (int e = 0; e < 4; ++e) {
            const int f = t + 256 * e;
            float4 v = src[f];
            float x[4] = {v.x, v.y, v.z, v.w};
            unsigned short o[4];
#pragma unroll
            for (int j = 0; j < 4; ++j) {
                float fv = x[j];
                as += fabsf(fv); qs += fv * fv; rs += fmaxf(fv, 0.f);
                o[j] = bfbits(fv);
            }
            dst[f] = make_ushort4(o[0], o[1], o[2], o[3]);
        }
        const int w = t >> 6, lane = t & 63;
        rs = wave_red(rs); as = wave_red(as); qs = wave_red(qs);
        if (lane == 0) { red[0][w] = rs; red[1][w] = as; red[2][w] = qs; }
        __syncthreads();
        if (t == 0) {
            rsT[i]   = red[0][0] + red[0][1] + red[0][2] + red[0][3];
            pAbsT[i] = red[1][0] + red[1][1] + red[1][2] + red[1][3];
            pSqT[i]  = red[2][0] + red[2][1] + red[2][2] + red[2][3];
        }
    } else if (b < 8192) {
        // ---- conv_s: incidence_s [N,N-1] -> zero-diag [N,N] bf16 + partials ----
        const int i = b - 4096;
        unsigned short* row = (unsigned short*)psm;
        float (*red)[4] = (float (*)[4])(psm + 8192);
        const float* srow = inc_s + (size_t)i * (NN - 1);
        float rs = 0.f, as = 0.f, qs = 0.f;
#pragma unroll
        for (int e = 0; e < 4; ++e) {
            const int f = t + 256 * e;
            float x[4] = {0.f, 0.f, 0.f, 0.f};
            if (f < 1023) __builtin_memcpy(x, srow + 4 * f, 16);
            else          __builtin_memcpy(x, srow + 4092, 12);
#pragma unroll
            for (int j = 0; j < 4; ++j) {
                const int k = 4 * f + j;
                float fv = x[j];
                as += fabsf(fv); qs += fv * fv; rs += fmaxf(fv, 0.f);
                if (k < NN - 1) row[k + (k >= i)] = bfbits(fv);
            }
        }
        if (t == 0) row[i] = 0;
        __syncthreads();
        uint4* dOut = (uint4*)(Ms + (size_t)i * NN);
        const uint4* sIn = (const uint4*)row;
        dOut[t] = sIn[t];
        dOut[t + 256] = sIn[t + 256];
        const int w = t >> 6, lane = t & 63;
        rs = wave_red(rs); as = wave_red(as); qs = wave_red(qs);
        if (lane == 0) { red[0][w] = rs; red[1][w] = as; red[2][w] = qs; }
        __syncthreads();
        if (t == 0) {
            rsS[i]   = red[0][0] + red[0][1] + red[0][2] + red[0][3];
            pAbsS[i] = red[1][0] + red[1][1] + red[1][2] + red[1][3];
            pSqS[i]  = red[2][0] + red[2][1] + red[2][2] + red[2][3];
        }
    } else if (b < 8704) {
        // ---- prep: 64x64 transpose tiles; cur/pre -> bf16 (+T) ----
        const int bb = b - 8192;
        const int x = bb & 63, y = (bb >> 6) & 3, z = bb >> 8;
        const int i0 = x * 64, d0 = y * 64;
        const float* src = z ? pre : cur;
        __bf16* dstT = z ? preT : curT;
        unsigned short (*tile)[72] = (unsigned short (*)[72])psm;
        const int r = t >> 2, c4 = (t & 3) * 16;
        const float* srow = src + (size_t)(i0 + r) * DD + d0 + c4;
        alignas(16) unsigned short loc[16];
#pragma unroll
        for (int e = 0; e < 4; ++e) {
            float4 v = ((const float4*)srow)[e];
            loc[e * 4 + 0] = bfbits(v.x);
            loc[e * 4 + 1] = bfbits(v.y);
            loc[e * 4 + 2] = bfbits(v.z);
            loc[e * 4 + 3] = bfbits(v.w);
        }
#pragma unroll
        for (int e = 0; e < 16; ++e) tile[r][c4 + e] = loc[e];
        if (z == 0) {
            __bf16* drow = cur_bf + (size_t)(i0 + r) * DD + d0 + c4;
            *(uint4*)drow = *(uint4*)&loc[0];
            *(uint4*)(drow + 8) = *(uint4*)&loc[8];
        }
        __syncthreads();
        alignas(16) unsigned short o[16];
#pragma unroll
        for (int e = 0; e < 16; ++e) o[e] = tile[c4 + e][r];
        __bf16* trow = dstT + (size_t)(d0 + r) * NN + i0 + c4;
        *(uint4*)trow = *(uint4*)&o[0];
        *(uint4*)(trow + 8) = *(uint4*)&o[8];
    } else {
        // ---- proj matrices -> bf16 (transposed for id<5) ----
        const int bb = b - 8704;
        const int id = bb >> 8, r = bb & 255;
        const float* src = id == 0 ? r_proj_s : id == 1 ? r_proj_t : id == 2 ? node_pj
                         : id == 3 ? spa_pj : id == 4 ? tmp_pj : theta_w;
        __bf16* dst = id == 0 ? pTs : id == 1 ? pTt : id == 2 ? pTn
                    : id == 3 ? pTspa : id == 4 ? pTtmp : thetaBf;
        float v = src[r * DD + t];
        if (id < 5) dst[t * DD + r] = (__bf16)v;
        else        dst[r * DD + t] = (__bf16)v;
    }
}

// ---------------- shared MFMA inner step for the small (padded-LDS) GEMMs ----------------
__device__ inline void mfma_step_s(const __bf16 (&As)[64][72], const __bf16 (&Bs)[64][72],
                                   int wr, int wc, int quad, int l16,
                                   f32x4 (&accR)[2][2]) {
#pragma unroll
    for (int ks = 0; ks < 2; ++ks) {
        const int kc = ks * 32 + quad * 8;
        bf16x8 a0 = *(const bf16x8*)&As[wr * 32 + l16][kc];
        bf16x8 a1 = *(const bf16x8*)&As[wr * 32 + 16 + l16][kc];
        bf16x8 b0 = *(const bf16x8*)&Bs[wc * 32 + l16][kc];
        bf16x8 b1 = *(const bf16x8*)&Bs[wc * 32 + 16 + l16][kc];
        accR[0][0] = MFMA16(a0, b0, accR[0][0]);
        accR[0][1] = MFMA16(a0, b1, accR[0][1]);
        accR[1][0] = MFMA16(a1, b0, accR[1][0]);
        accR[1][1] = MFMA16(a1, b1, accR[1][1]);
    }
}

// ---------------- big dual GEMM, K-split across waves ----------------
// Each wave computes the full 64x64 tile for its K=16 slice with 32x32x16 MFMA
// (A and B each read from LDS exactly once per block), 4-buffer global_load_lds
// pipeline with counted vmcnt(8), 2 K-tiles per barrier pair, cross-wave LDS
// reduce in epilogue. XCD-chunked block swizzle for A-panel L2 reuse.
__global__ __launch_bounds__(256, 2) void k_big(const __bf16* __restrict__ Mt, const __bf16* __restrict__ Ms,
                                                const __bf16* __restrict__ preT, const __bf16* __restrict__ curT,
                                                const float* __restrict__ negMt, const float* __restrict__ negMs,
                                                const float* __restrict__ cur,
                                                const float* __restrict__ rsT, const float* __restrict__ rsS,
                                                __bf16* __restrict__ embT, __bf16* __restrict__ embS,
                                                float* __restrict__ pDiff) {
    const int flat = blockIdx.x + 4 * (blockIdx.y + 64 * blockIdx.z);
    const int swz = (flat & 7) * 64 + (flat >> 3);
    const int bx = swz & 3, by = (swz >> 2) & 63, z = swz >> 8;
    const __bf16* A  = z ? Ms : Mt;
    const __bf16* BT = z ? curT : preT;
    const float* negM = z ? negMs : negMt;
    const float* rs   = z ? rsS : rsT;
    __bf16* emb       = z ? embS : embT;
    const int n0 = bx * 64, m0 = by * 64;
    __shared__ __align__(16) char smraw[65536];
    __bf16 (*sm)[2][64][64] = (__bf16 (*)[2][64][64])smraw;   // [buf][A/B][row][col]
    float* scr = (float*)smraw;                               // reduce scratch (overlays bufs 0,1)
    f32x16 accR[2][2], accL[2][2];
#pragma unroll
    for (int i = 0; i < 2; ++i)
#pragma unroll
        for (int j = 0; j < 2; ++j) { accR[i][j] = (f32x16)0.f; accL[i][j] = (f32x16)0.f; }
    const int t = threadIdx.x, w = t >> 6, lane = t & 63;
    // staging: wave w stages row-chunks {2w,2w+1} of A and B; source chunk pre-XOR'd
    // by row (rule #21 both-sides) so reads XOR by (row&7) on a linear LDS tile.
    const int lr = lane >> 3, lc = lane & 7;
    const int q0 = 2 * w, q1 = q0 + 1;
    const int csw = (lc ^ lr) * 8;
    const __bf16* gA0 = A + (size_t)(m0 + 8 * q0 + lr) * NN + csw;
    const __bf16* gA1 = A + (size_t)(m0 + 8 * q1 + lr) * NN + csw;
    const __bf16* gB0 = BT + (size_t)(n0 + 8 * q0 + lr) * NN + csw;
    const __bf16* gB1 = BT + (size_t)(n0 + 8 * q1 + lr) * NN + csw;
    auto stage = [&](int b, int tk) {
        const int ko = tk * 64;
        GLD16(gA0 + ko, &sm[b][0][8 * q0][0]);
        GLD16(gA1 + ko, &sm[b][0][8 * q1][0]);
        GLD16(gB0 + ko, &sm[b][1][8 * q0][0]);
        GLD16(gB1 + ko, &sm[b][1][8 * q1][0]);
    };
    stage(0, 0); stage(1, 1); stage(2, 2); stage(3, 3);
    asm volatile("s_waitcnt vmcnt(8)" ::: "memory");          // tiles 0,1 landed
    __builtin_amdgcn_s_barrier();
    __builtin_amdgcn_sched_barrier(0);
    // fragment addressing (32x32x16): A row = lane&31 (+32*mi), k = 16*w + (lane>>5)*8
    const int fr = lane & 31, h = lane >> 5;
    const int swc = ((2 * w + h) ^ (fr & 7)) * 8;             // swizzled 16B chunk (constant)
    for (int it = 0; it < 32; ++it) {
        const int b0 = (2 * it) & 3, b1 = b0 + 1;
        bf16x8 a[2][2], bb[2][2];
#pragma unroll
        for (int mi = 0; mi < 2; ++mi) {
            a[0][mi]  = *(const bf16x8*)&sm[b0][0][mi * 32 + fr][swc];
            a[1][mi]  = *(const bf16x8*)&sm[b1][0][mi * 32 + fr][swc];
            bb[0][mi] = *(const bf16x8*)&sm[b0][1][mi * 32 + fr][swc];
            bb[1][mi] = *(const bf16x8*)&sm[b1][1][mi * 32 + fr][swc];
        }
        asm volatile("s_waitcnt lgkmcnt(0)" ::: "memory");    // fragments in regs
        __builtin_amdgcn_sched_barrier(0);
        __builtin_amdgcn_s_barrier();                         // bufs b0,b1 free
        __builtin_amdgcn_sched_barrier(0);
        if (it < 30) { stage(b0, 2 * it + 4); stage(b1, 2 * it + 5); }
        __builtin_amdgcn_sched_barrier(0);
        __builtin_amdgcn_s_setprio(1);
#pragma unroll
        for (int u = 0; u < 2; ++u)
#pragma unroll
            for (int mi = 0; mi < 2; ++mi) {
                bf16x8 ar = brelu(a[u][mi]);
#pragma unroll
                for (int ni = 0; ni < 2; ++ni) {
                    accR[mi][ni] = MFMA32(a[u][mi], bb[u][ni], accR[mi][ni]);
                    accL[mi][ni] = MFMA32(ar,       bb[u][ni], accL[mi][ni]);
                }
            }
        __builtin_amdgcn_s_setprio(0);
        if (it < 31) {
            if (it < 30) asm volatile("s_waitcnt vmcnt(8)" ::: "memory");   // next pair landed
            else         asm volatile("s_waitcnt vmcnt(0)" ::: "memory");
            __builtin_amdgcn_s_barrier();
            __builtin_amdgcn_sched_barrier(0);
        }
    }
    // cross-wave reduce: wave w owns quadrant (w>>1, w&1)
    f32x16 oR, oL;
    if      (w == 0) red_owner<0>(accR, accL, scr, lane, oR, oL);
    else if (w == 1) red_owner<1>(accR, accL, scr, lane, oR, oL);
    else if (w == 2) red_owner<2>(accR, accL, scr, lane, oR, oL);
    else             red_owner<3>(accR, accL, scr, lane, oR, oL);
    const int mi = w >> 1, ni = w & 1;
    float sumd = 0.f;
#pragma unroll
    for (int reg = 0; reg < 16; ++reg) {
        const int rr = (reg & 3) + 8 * (reg >> 2) + 4 * h;
        const int gr = m0 + mi * 32 + rr;
        const int gc = n0 + ni * 32 + fr;
        const size_t idx = (size_t)gr * DD + gc;
        float diff = oR[reg] + negM[idx];                     // recon - master
        sumd += diff * diff;
        emb[idx] = (__bf16)((oL[reg] + cur[idx]) * (1.f / (rs[gr] + 1.f)));
    }
    sumd = wave_red(sumd);
    float* sredp = (float*)(smraw + 32768);                   // bufs 2,3 region (free)
    if (lane == 0) sredp[w] = sumd;
    __syncthreads();
    if (t == 0)
        pDiff[z * 256 + by * 4 + bx] = sredp[0] + sredp[1] + sredp[2] + sredp[3];
}

// ---------------- small GEMMs: -master_s, -master_t, node_fea ----------------
__global__ __launch_bounds__(256) void k_small3(const __bf16* __restrict__ cur_bf,
                                                const __bf16* __restrict__ pTs, const __bf16* __restrict__ pTt,
                                                const __bf16* __restrict__ pTn,
                                                float* __restrict__ negMs, float* __restrict__ negMt,
                                                float* __restrict__ nodeFea) {
    const int z = blockIdx.z;
    const __bf16* BT = z == 0 ? pTs : (z == 1 ? pTt : pTn);
    const int n0 = blockIdx.x * 64, m0 = blockIdx.y * 64;
    __shared__ __bf16 As[64][72], Bs[64][72];
    f32x4 accR[2][2];
#pragma unroll
    for (int i = 0; i < 2; ++i)
#pragma unroll
        for (int j = 0; j < 2; ++j) accR[i][j] = (f32x4)0.f;
    const int t = threadIdx.x, w = t >> 6, lane = t & 63, quad = lane >> 4, l16 = lane & 15;
    const int wr = w >> 1, wc = w & 1;
    const int sr = t >> 2, sc = (t & 3) * 16;
    const __bf16* gA = cur_bf + (size_t)(m0 + sr) * DD + sc;
    const __bf16* gB = BT + (size_t)(n0 + sr) * DD + sc;
    for (int kt = 0; kt < DD / 64; ++kt) {
        uint4 av0 = *(const uint4*)(gA);
        uint4 av1 = *(const uint4*)(gA + 8);
        uint4 bv0 = *(const uint4*)(gB);
        uint4 bv1 = *(const uint4*)(gB + 8);
        __syncthreads();
        *(uint4*)&As[sr][sc] = av0; *(uint4*)&As[sr][sc + 8] = av1;
        *(uint4*)&Bs[sr][sc] = bv0; *(uint4*)&Bs[sr][sc + 8] = bv1;
        __syncthreads();
        mfma_step_s(As, Bs, wr, wc, quad, l16, accR);
        gA += 64; gB += 64;
    }
#pragma unroll
    for (int mi = 0; mi < 2; ++mi)
#pragma unroll
        for (int ni = 0; ni < 2; ++ni)
#pragma unroll
            for (int r = 0; r < 4; ++r) {
                int gr = m0 + wr * 32 + mi * 16 + quad * 4 + r;
                int gc = n0 + wc * 32 + ni * 16 + l16;
                size_t idx = (size_t)gr * DD + gc;
                float v = accR[mi][ni][r];
                if (z == 0) negMs[idx] = -v;
                else if (z == 1) negMt[idx] = -v;
                else nodeFea[idx] = v;
            }
}

// ---------------- edge-feature projections + fused attention partial dots ----------------
__global__ __launch_bounds__(256) void k_fea(const __bf16* __restrict__ embS, const __bf16* __restrict__ embT,
                                             const __bf16* __restrict__ pTspa, const __bf16* __restrict__ pTtmp,
                                             const float* __restrict__ nodeF,
                                             float* __restrict__ spaF, float* __restrict__ tmpF,
                                             float* __restrict__ pSpa, float* __restrict__ pTmp) {
    const int z = blockIdx.z;
    const __bf16* Ae = z ? embT : embS;
    const __bf16* BT = z ? pTtmp : pTspa;
    float* outF = z ? tmpF : spaF;
    float* pOut = z ? pTmp : pSpa;
    const int n0 = blockIdx.x * 64, m0 = blockIdx.y * 64;
    __shared__ __bf16 As[64][72], Bs[64][72];
    f32x4 accR[2][2];
#pragma unroll
    for (int i = 0; i < 2; ++i)
#pragma unroll
        for (int j = 0; j < 2; ++j) accR[i][j] = (f32x4)0.f;
    const int t = threadIdx.x, w = t >> 6, lane = t & 63, quad = lane >> 4, l16 = lane & 15;
    const int wr = w >> 1, wc = w & 1;
    const int sr = t >> 2, sc = (t & 3) * 16;
    const __bf16* gA = Ae + (size_t)(m0 + sr) * DD + sc;
    const __bf16* gB = BT + (size_t)(n0 + sr) * DD + sc;
    for (int kt = 0; kt < DD / 64; ++kt) {
        uint4 av0 = *(const uint4*)(gA);
        uint4 av1 = *(const uint4*)(gA + 8);
        uint4 bv0 = *(const uint4*)(gB);
        uint4 bv1 = *(const uint4*)(gB + 8);
        __syncthreads();
        *(uint4*)&As[sr][sc] = av0; *(uint4*)&As[sr][sc + 8] = av1;
        *(uint4*)&Bs[sr][sc] = bv0; *(uint4*)&Bs[sr][sc + 8] = bv1;
        __syncthreads();
        mfma_step_s(As, Bs, wr, wc, quad, l16, accR);
        gA += 64; gB += 64;
    }
    const int slice = blockIdx.x * 2 + wc;
#pragma unroll
    for (int mi = 0; mi < 2; ++mi)
#pragma unroll
        for (int r = 0; r < 4; ++r) {
            const int gr = m0 + wr * 32 + mi * 16 + quad * 4 + r;
            float s = 0.f;
#pragma unroll
            for (int ni = 0; ni < 2; ++ni) {
                const int gc = n0 + wc * 32 + ni * 16 + l16;
                const size_t idx = (size_t)gr * DD + gc;
                const float v = accR[mi][ni][r];
                outF[idx] = v;
                s += v * nodeF[idx];
            }
            s += __shfl_xor(s, 1, 64);
            s += __shfl_xor(s, 2, 64);
            s += __shfl_xor(s, 4, 64);
            s += __shfl_xor(s, 8, 64);
            if (l16 == 0) pOut[(size_t)slice * NN + gr] = s;
        }
}

// ---------------- final: val @ theta_w^T + b, relu -> d_out (+ fused loss in block 0) ----------------
__global__ __launch_bounds__(256) void k_final(const float* __restrict__ spaF, const float* __restrict__ tmpF,
                                               const float* __restrict__ pSpa, const float* __restrict__ pTmp,
                                               const __bf16* __restrict__ thetaBf, const float* __restrict__ thetaB,
                                               const float* __restrict__ pAbsT, const float* __restrict__ pSqT,
                                               const float* __restrict__ pAbsS, const float* __restrict__ pSqS,
                                               const float* __restrict__ pDiff,
                                               float* __restrict__ out) {
    const int n0 = blockIdx.x * 64, m0 = blockIdx.y * 64;
    __shared__ __bf16 As[64][72], Bs[64][72];
    f32x4 accR[2][2];
#pragma unroll
    for (int i = 0; i < 2; ++i)
#pragma unroll
        for (int j = 0; j < 2; ++j) accR[i][j] = (f32x4)0.f;
    const int t = threadIdx.x, w = t >> 6, lane = t & 63, quad = lane >> 4, l16 = lane & 15;
    const int wr = w >> 1, wc = w & 1;
    const int sr = t >> 2, sc = (t & 3) * 16;
    const int row = m0 + sr;
    float sa = 0.f, ta = 0.f;
#pragma unroll
    for (int j = 0; j < 8; ++j) {
        sa += pSpa[(size_t)j * NN + row];
        ta += pTmp[(size_t)j * NN + row];
    }
    sa *= 0.0625f; ta *= 0.0625f;   // 1/sqrt(256)
    const float* gS = spaF + (size_t)row * DD + sc;
    const float* gT = tmpF + (size_t)row * DD + sc;
    const __bf16* gB = thetaBf + (size_t)(n0 + sr) * DD + sc;
    for (int kt = 0; kt < DD / 64; ++kt) {
        __bf16 tmp[16];
#pragma unroll
        for (int e4 = 0; e4 < 4; ++e4) {
            float4 vs = ((const float4*)gS)[e4];
            float4 vt = ((const float4*)gT)[e4];
            tmp[e4 * 4 + 0] = (__bf16)(sa * vs.x + ta * vt.x);
            tmp[e4 * 4 + 1] = (__bf16)(sa * vs.y + ta * vt.y);
            tmp[e4 * 4 + 2] = (__bf16)(sa * vs.z + ta * vt.z);
            tmp[e4 * 4 + 3] = (__bf16)(sa * vs.w + ta * vt.w);
        }
        uint4 bv0 = *(const uint4*)(gB);
        uint4 bv1 = *(const uint4*)(gB + 8);
        __syncthreads();
        *(uint4*)&As[sr][sc] = *(uint4*)&tmp[0]; *(uint4*)&As[sr][sc + 8] = *(uint4*)&tmp[8];
        *(uint4*)&Bs[sr][sc] = bv0; *(uint4*)&Bs[sr][sc + 8] = bv1;
        __syncthreads();
        mfma_step_s(As, Bs, wr, wc, quad, l16, accR);
        gS += 64; gT += 64; gB += 64;
    }
#pragma unroll
    for (int mi = 0; mi < 2; ++mi)
#pragma unroll
        for (int ni = 0; ni < 2; ++ni)
#pragma unroll
            for (int r = 0; r < 4; ++r) {
                int gr = m0 + wr * 32 + mi * 16 + quad * 4 + r;
                int gc = n0 + wc * 32 + ni * 16 + l16;
                float v = accR[mi][ni][r] + thetaB[gc];
                out[(size_t)gr * DD + gc] = fmaxf(v, 0.f);
            }
    // ---- fused loss (one block) ----
    if (blockIdx.x == 0 && blockIdx.y == 0) {
        float aT = 0.f, qT = 0.f, aS = 0.f, qS = 0.f;
#pragma unroll
        for (int j = 0; j < 16; ++j) {
            const int i = t + 256 * j;
            aT += pAbsT[i]; qT += pSqT[i]; aS += pAbsS[i]; qS += pSqS[i];
        }
        float dT = pDiff[t], dS = pDiff[256 + t];
        aT = wave_red(aT); qT = wave_red(qT); aS = wave_red(aS); qS = wave_red(qS);
        dT = wave_red(dT); dS = wave_red(dS);
        float (*red)[4] = (float (*)[4])As;
        if (lane == 0) { red[0][w] = aT; red[1][w] = qT; red[2][w] = aS; red[3][w] = qS; red[4][w] = dT; red[5][w] = dS; }
        __syncthreads();
        if (t == 0) {
            float s[6];
#pragma unroll
            for (int k = 0; k < 6; ++k) s[k] = red[k][0] + red[k][1] + red[k][2] + red[k][3];
            float l = s[0] + 0.001f * sqrtf(s[1]) + 0.2f * sqrtf(s[4])    // temporal
                    + s[2] + 0.001f * sqrtf(s[3]) + 0.2f * sqrtf(s[5]);   // spatial
            out[(size_t)NN * DD] = l;
        }
    }
}

extern "C" void kernel_launch(void* const* d_in, const int* in_sizes, int n_in,
                              void* d_out, int out_size, void* d_ws, size_t ws_size,
                              hipStream_t stream) {
    (void)in_sizes; (void)n_in; (void)out_size; (void)ws_size;
    const float* cur      = (const float*)d_in[0];
    const float* pre      = (const float*)d_in[1];
    const float* r_proj_s = (const float*)d_in[2];
    const float* inc_s    = (const float*)d_in[3];
    const float* r_proj_t = (const float*)d_in[4];
    const float* inc_t    = (const float*)d_in[5];
    const float* node_pj  = (const float*)d_in[6];
    const float* spa_pj   = (const float*)d_in[7];
    const float* tmp_pj   = (const float*)d_in[8];
    const float* theta_w  = (const float*)d_in[9];
    const float* theta_b  = (const float*)d_in[10];
    float* out = (float*)d_out;

    char* p = (char*)d_ws;
    auto alloc = [&](size_t bytes) -> void* {
        void* r = (void*)p;
        p += (bytes + 255) & ~(size_t)255;
        return r;
    };
    __bf16* Mt      = (__bf16*)alloc((size_t)NN * NN * 2);
    __bf16* Ms      = (__bf16*)alloc((size_t)NN * NN * 2);
    __bf16* cur_bf  = (__bf16*)alloc((size_t)NN * DD * 2);
    __bf16* curT    = (__bf16*)alloc((size_t)NN * DD * 2);
    __bf16* preT    = (__bf16*)alloc((size_t)NN * DD * 2);
    __bf16* pTs     = (__bf16*)alloc((size_t)DD * DD * 2);
    __bf16* pTt     = (__bf16*)alloc((size_t)DD * DD * 2);
    __bf16* pTn     = (__bf16*)alloc((size_t)DD * DD * 2);
    __bf16* pTspa   = (__bf16*)alloc((size_t)DD * DD * 2);
    __bf16* pTtmp   = (__bf16*)alloc((size_t)DD * DD * 2);
    __bf16* thetaBf = (__bf16*)alloc((size_t)DD * DD * 2);
    __bf16* embS    = (__bf16*)alloc((size_t)NN * DD * 2);
    __bf16* embT    = (__bf16*)alloc((size_t)NN * DD * 2);
    float* negMs    = (float*)alloc((size_t)NN * DD * 4);
    float* negMt    = (float*)alloc((size_t)NN * DD * 4);
    float* nodeFea  = (float*)alloc((size_t)NN * DD * 4);
    float* spaF     = (float*)alloc((size_t)NN * DD * 4);
    float* tmpF     = (float*)alloc((size_t)NN * DD * 4);
    float* rsS      = (float*)alloc((size_t)NN * 4);
    float* rsT      = (float*)alloc((size_t)NN * 4);
    float* pSpa     = (float*)alloc((size_t)8 * NN * 4);
    float* pTmp     = (float*)alloc((size_t)8 * NN * 4);
    float* pAbsT    = (float*)alloc((size_t)NN * 4);
    float* pSqT     = (float*)alloc((size_t)NN * 4);
    float* pAbsS    = (float*)alloc((size_t)NN * 4);
    float* pSqS     = (float*)alloc((size_t)NN * 4);
    float* pDiff    = (float*)alloc(512 * 4);

    k_pre<<<10240, 256, 0, stream>>>(cur, pre, r_proj_s, r_proj_t, node_pj, spa_pj, tmp_pj, theta_w,
                                     inc_t, inc_s,
                                     cur_bf, curT, preT, pTs, pTt, pTn, pTspa, pTtmp, thetaBf,
                                     Mt, Ms, rsT, pAbsT, pSqT, rsS, pAbsS, pSqS);
    k_small3<<<dim3(4, 64, 3), 256, 0, stream>>>(cur_bf, pTs, pTt, pTn, negMs, negMt, nodeFea);
    k_big<<<dim3(4, 64, 2), 256, 0, stream>>>(Mt, Ms, preT, curT, negMt, negMs, cur,
                                              rsT, rsS, embT, embS, pDiff);
    k_fea<<<dim3(4, 64, 2), 256, 0, stream>>>(embS, embT, pTspa, pTtmp, nodeFea,
                                              spaF, tmpF, pSpa, pTmp);
    k_final<<<dim3(4, 64), 256, 0, stream>>>(spaF, tmpF, pSpa, pTmp, thetaBf, theta_b,
                                             pAbsT, pSqT, pAbsS, pSqS, pDiff, out);
}